// Round 17
// baseline (172.800 us; speedup 1.0000x reference)
//
#include <hip/hip_runtime.h>
#include <math.h>

#define N_NODES 20000
#define N_EDGES 320000
#define HID 16
#define OMEGA 100.0f
#define BETA 0.2f
#define REVC 0.15915494309189535f

// P layout (float/u32 indices)
#define OFF_B1  64     // 16 floats (prescaled)
#define OFF_B2  80     // 16 floats
#define OFF_A2  128    // uint4[64]: W2 A-frags, [hi|lo] K-packed
#define OFF_AO  896    // per o: 512 u32 (Ah uint4[64], Al uint4[64])
#define OFF_H2V 9088   // O*16 floats
#define P_SIZE  9472

typedef float  f32x4 __attribute__((ext_vector_type(4)));
typedef short  s16x8 __attribute__((ext_vector_type(8)));

__device__ __forceinline__ float sinrev(float x) { return __builtin_amdgcn_sinf(x); }
__device__ __forceinline__ float cosrev(float x) { return __builtin_amdgcn_cosf(x); }
__device__ __forceinline__ float fract_f(float x) { return __builtin_amdgcn_fractf(x); }

__device__ __forceinline__ float selu_f(float v) {
    const float a  = 1.6732632423543772f;
    const float sc = 1.0507009873554805f;
    return sc * (v > 0.f ? v : a * expm1f(v));
}

__device__ __forceinline__ f32x4 mfma16(s16x8 a, s16x8 b, f32x4 c) {
    return __builtin_amdgcn_mfma_f32_16x16x32_bf16(a, b, c, 0, 0, 0);
}

__device__ __forceinline__ unsigned pk_hi(float a, float b) {
    return (__float_as_uint(b) & 0xFFFF0000u) | (__float_as_uint(a) >> 16);
}
__device__ __forceinline__ float lo_of(float a) {
    return a - __uint_as_float(__float_as_uint(a) & 0xFFFF0000u);
}

union U4 { uint4 v; s16x8 s; };

// ---------------------------------------------------------------- prep (3 blocks, 1 per conv)
struct PrepArgs {
    const float* w0[3]; const float* b0[3]; const float* w1[3]; const float* b1[3];
    const float* w2[3]; const float* b2[3];
    float* P[3];
};

__global__ __launch_bounds__(256) void prep_kernel(PrepArgs A)
{
    const int OUTS[3] = {8, 8, 16};
    int c = blockIdx.x;
    int OUT = OUTS[c];
    const float* w0 = A.w0[c]; const float* b0 = A.b0[c];
    const float* w1 = A.w1[c]; const float* b1 = A.b1[c];
    const float* w2 = A.w2[c]; const float* b2 = A.b2[c];
    float* P = A.P[c];
    unsigned* Pu = (unsigned*)P;

    __shared__ float W1s[256], W2s[256], cosB[256], sinB[256], w0c[16];
    int t = threadIdx.x;
    const float s = OMEGA * REVC;
    W1s[t] = s * w1[t];
    W2s[t] = s * w2[t];
    if (t < 16) w0c[t] = s * w0[t * 4 + 3];
    __syncthreads();

    if (t < 64) { int h = t >> 2, k = t & 3; P[t] = (k < 3) ? s * w0[h * 4 + k] : s * b0[h]; }
    if (t >= 64 && t < 80)  P[t] = s * b1[t - 64];
    if (t >= 80 && t < 96)  P[t] = s * b2[t - 80];

    if (t < OUT * 16) {
        int o = t >> 4, h = t & 15;
        float ang = fract_f((float)o * w0c[h]);
        cosB[t] = cosrev(ang);
        sinB[t] = sinrev(ang);
    }
    __syncthreads();

    // W2 A-frags (K-packed hi|lo): lane (g,q), k=8q+e: e<4 -> hi(W2[g,4q+e]), e>=4 -> lo
    if (t < 64) {
        int g = t & 15, q = t >> 4;
        float w[4], l[4];
#pragma unroll
        for (int j = 0; j < 4; j++) { w[j] = W2s[g * 16 + 4 * q + j]; l[j] = lo_of(w[j]); }
        ((uint4*)(Pu + OFF_A2))[t] = make_uint4(pk_hi(w[0], w[1]), pk_hi(w[2], w[3]),
                                                pk_hi(l[0], l[1]), pk_hi(l[2], l[3]));
    }
    // Per-channel L2 A-matrices: A_o[g,k] = k<16 ? W1[g,k]*cosB[o,k] : W1[g,k-16]*sinB[o,k-16]
    for (int idx = t; idx < OUT * 64; idx += 256) {
        int o = idx >> 6, lane = idx & 63, g = lane & 15, q = lane >> 4;
        float v[8], l[8];
#pragma unroll
        for (int e = 0; e < 8; e++) {
            int k = 8 * q + e;
            float a = (k < 16) ? W1s[g * 16 + k] * cosB[o * 16 + k]
                               : W1s[g * 16 + (k - 16)] * sinB[o * 16 + (k - 16)];
            v[e] = a; l[e] = lo_of(a);
        }
        ((uint4*)(Pu + OFF_AO + o * 512))[lane] =
            make_uint4(pk_hi(v[0], v[1]), pk_hi(v[2], v[3]), pk_hi(v[4], v[5]), pk_hi(v[6], v[7]));
        ((uint4*)(Pu + OFF_AO + o * 512 + 256))[lane] =
            make_uint4(pk_hi(l[0], l[1]), pk_hi(l[2], l[3]), pk_hi(l[4], l[5]), pk_hi(l[6], l[7]));
    }
    // self-loop h2 chain (feat=0), fp32 exact
    if (t < OUT) {
        float oc = (float)t;
        float h0[HID], h1[HID];
#pragma unroll
        for (int h = 0; h < HID; h++)
            h0[h] = sinrev(fract_f(fmaf(oc, w0c[h], s * b0[h])));
#pragma unroll
        for (int g = 0; g < HID; g++) {
            float sa = s * b1[g];
#pragma unroll
            for (int h = 0; h < HID; h++) sa += h0[h] * W1s[g * HID + h];
            h1[g] = sinrev(sa);
        }
#pragma unroll
        for (int g = 0; g < HID; g++) {
            float sa = s * b2[g];
#pragma unroll
            for (int h = 0; h < HID; h++) sa += h1[h] * W2s[g * HID + h];
            P[OFF_H2V + t * HID + g] = sinrev(sa);
        }
    }
}

// ---------------------------------------------------------------- fused pre: feat + xcat + tself1
__global__ __launch_bounds__(256) void fused_pre_kernel(
    const int* __restrict__ ei, const float* __restrict__ pos,
    const float* __restrict__ x,
    float4* __restrict__ feat, float* __restrict__ xcat,
    const float* __restrict__ wl1, const float* __restrict__ bl1,
    float* __restrict__ tb, float* __restrict__ blxb)
{
    int b = blockIdx.x;
    if (b < 1250) {
        int e = b * 256 + threadIdx.x;
        if (e >= N_EDGES) return;
        int s = ei[e], d = ei[N_EDGES + e];
        float rx = pos[d * 3 + 0] - pos[s * 3 + 0];
        float ry = pos[d * 3 + 1] - pos[s * 3 + 1];
        float rz = pos[d * 3 + 2] - pos[s * 3 + 2];
        float sq = rx * rx + ry * ry + rz * rz;
        float4 f = make_float4(0.f, 0.f, 0.f, 0.f);
        if (sq > 0.f) {
            float rho = sqrtf(sq);
            float th  = atan2f(ry, rx);
            float ph  = asinf(fminf(fmaxf(rz / rho, -1.f), 1.f));
            const float inv_pi = 0.31830988618379067f;
            f = make_float4(rho, th * inv_pi, ph * inv_pi, 0.f);
        }
        feat[e] = f;
    } else if (b < 2500) {
        int i = (b - 1250) * 256 + threadIdx.x;
        if (i >= N_NODES * 16) return;
        int n = i >> 4, cc = i & 15;
        xcat[n * 32 + cc] = x[i];
    } else {
        int n = (b - 2500) * 256 + threadIdx.x;
        if (n >= N_NODES) return;
        float tn[HID];
#pragma unroll
        for (int h = 0; h < HID; h++) tn[h] = 0.f;
        float bx = 0.f;
#pragma unroll
        for (int i = 0; i < 16; i++) {
            float xi = x[n * 16 + i];
            bx += bl1[i] * xi;
#pragma unroll
            for (int h = 0; h < HID; h++) tn[h] += wl1[i * 16 + h] * xi;
        }
#pragma unroll
        for (int h = 0; h < HID; h++) tb[n * 16 + h] = tn[h];
        blxb[n] = bx;
    }
}

// ---------------------------------------------------------------- conv: wave = 16 edges, loop o
// One shfl_xor(32) per o merges q-pairs (q0+q2, q1+q3) -> sm halves to 2 partials.
// Epilogue sums 2 q-partials during transposed channel-contiguous atomic emission.
template<int OUT>
__global__ __launch_bounds__(256) void conv_kernel(
    const int* __restrict__ ei, const float4* __restrict__ feat,
    const float* __restrict__ tbn, const float* __restrict__ blxn,
    const float* __restrict__ P, float* __restrict__ acc)
{
    constexpr int L2O = (OUT == 16) ? 4 : 3;
    constexpr int EPI = 64 / OUT;     // edges per atomic instruction
    constexpr int NI  = 16 / EPI;     // atomic instructions per wave

    __shared__ float sm[4][OUT * 2 * 17];
    const unsigned* Pu = (const unsigned*)P;
    int wslot = threadIdx.x >> 6;
    int wid  = (blockIdx.x * 256 + threadIdx.x) >> 6;
    int lane = threadIdx.x & 63;
    int e16 = lane & 15, q = lane >> 4;
    int e = wid * 16 + e16;
    int src = ei[e];
    int dst = ei[N_EDGES + e];
    float4 f = feat[e];

    // T, bx: gathered from per-node tables (exact fp32)
    f32x4 T = *(const f32x4*)(tbn + src * 16 + 4 * q);
    float bx = blxn[src];

    // L1: 8 angles (h-octet (q&1)*8); q<2 -> sin, q>=2 -> cos. B-frag k=8q+e.
    float tr[8];
    {
        const float4* w0i = (const float4*)P;
        int hb = (q & 1) * 8;
#pragma unroll
        for (int j = 0; j < 8; j++) {
            float4 w = w0i[hb + j];
            float ang = fract_f(w.w + f.x * w.x + f.y * w.y + f.z * w.z);
            tr[j] = (q < 2) ? sinrev(ang) : cosrev(ang);
        }
    }
    U4 Bh, Bl;
    Bh.v = make_uint4(pk_hi(tr[0], tr[1]), pk_hi(tr[2], tr[3]),
                      pk_hi(tr[4], tr[5]), pk_hi(tr[6], tr[7]));
    Bl.v = make_uint4(pk_hi(lo_of(tr[0]), lo_of(tr[1])), pk_hi(lo_of(tr[2]), lo_of(tr[3])),
                      pk_hi(lo_of(tr[4]), lo_of(tr[5])), pk_hi(lo_of(tr[6]), lo_of(tr[7])));

    U4 A2; A2.v = ((const uint4*)(Pu + OFF_A2))[lane];
    f32x4 c1 = *(const f32x4*)(P + OFF_B1 + 4 * q);
    f32x4 c2 = *(const f32x4*)(P + OFF_B2 + 4 * q);

#pragma unroll 2
    for (int o = 0; o < OUT; ++o) {
        U4 Ah, Al;
        Ah.v = ((const uint4*)(Pu + OFF_AO + o * 512))[lane];
        Al.v = ((const uint4*)(Pu + OFF_AO + o * 512 + 256))[lane];
        f32x4 D = c1;
        D = mfma16(Ah.s, Bh.s, D);
        D = mfma16(Ah.s, Bl.s, D);
        D = mfma16(Al.s, Bh.s, D);
        float h1[4];
#pragma unroll
        for (int j = 0; j < 4; j++) h1[j] = sinrev(D[j]);
        unsigned p0 = pk_hi(h1[0], h1[1]), p1 = pk_hi(h1[2], h1[3]);
        unsigned l0 = pk_hi(lo_of(h1[0]), lo_of(h1[1])), l1 = pk_hi(lo_of(h1[2]), lo_of(h1[3]));
        U4 Ph, Pl;
        Ph.v = make_uint4(p0, p1, p0, p1);
        Pl.v = make_uint4(l0, l1, l0, l1);
        f32x4 D2 = c2;
        D2 = mfma16(A2.s, Ph.s, D2);
        D2 = mfma16(A2.s, Pl.s, D2);
        // per-q partial; merge q-pairs (q0+q2, q1+q3) with one shuffle
        float p = sinrev(D2[0]) * T[0] + sinrev(D2[1]) * T[1]
                + sinrev(D2[2]) * T[2] + sinrev(D2[3]) * T[3];
        if (q == 0) p += bx;
        p += __shfl_xor(p, 32);
        if (lane < 32)
            sm[wslot][(q * OUT + o) * 17 + e16] = p;   // q in {0,1}
    }

    // transposed atomic emission: lane = (edge-in-group, channel); sum 2 q-partials
    int oo = lane & (OUT - 1);
    int el = lane >> L2O;
#pragma unroll
    for (int j = 0; j < NI; j++) {
        int ej = j * EPI + el;
        int dj = __shfl(dst, ej);
        float v = sm[wslot][(0 * OUT + oo) * 17 + ej] + sm[wslot][(1 * OUT + oo) * 17 + ej];
        atomicAdd(&acc[dj * OUT + oo], v);
    }
}

// ---------------------------------------------------------------- finishers (per node)
template<int OUT, int CO>
__global__ __launch_bounds__(256) void finish_mid_kernel(
    const float* __restrict__ acc, const float* __restrict__ bias,
    const float* __restrict__ h2v,
    float* __restrict__ tb, float* __restrict__ blxb,
    float* __restrict__ xcat,
    const float* __restrict__ wlN, const float* __restrict__ blN)
{
    int n = blockIdx.x * 256 + threadIdx.x;
    if (n >= N_NODES) return;
    float trr[HID];
#pragma unroll
    for (int h = 0; h < HID; h++) trr[h] = tb[n * 16 + h];
    float bx = blxb[n];
    float xrow[CO + OUT];
#pragma unroll
    for (int i = 0; i < CO; i++) xrow[i] = xcat[n * 32 + i];
#pragma unroll
    for (int o = 0; o < OUT; o++) {
        float m = bx;
#pragma unroll
        for (int h = 0; h < HID; h++) m += h2v[o * 16 + h] * trr[h];
        float v = selu_f(acc[n * OUT + o] + bias[o] + m);
        xrow[CO + o] = v;
        xcat[n * 32 + CO + o] = v;
    }
    float tn[HID];
#pragma unroll
    for (int h = 0; h < HID; h++) tn[h] = 0.f;
    float bxn = 0.f;
#pragma unroll
    for (int i = 0; i < CO + OUT; i++) {
        float xi = xrow[i];
        bxn += blN[i] * xi;
#pragma unroll
        for (int h = 0; h < HID; h++) tn[h] += wlN[i * 16 + h] * xi;
    }
#pragma unroll
    for (int h = 0; h < HID; h++) tb[n * 16 + h] = tn[h];
    blxb[n] = bxn;
}

__global__ __launch_bounds__(256) void finish_out_kernel(
    const float* __restrict__ acc, const float* __restrict__ bias,
    const float* __restrict__ h2v,
    const float* __restrict__ tb, const float* __restrict__ blxb,
    const float* __restrict__ x, float* __restrict__ out)
{
    int n = blockIdx.x * 256 + threadIdx.x;
    if (n >= N_NODES) return;
    float trr[HID];
#pragma unroll
    for (int h = 0; h < HID; h++) trr[h] = tb[n * 16 + h];
    float bx = blxb[n];
#pragma unroll
    for (int c = 0; c < 16; c++) {
        float m = bx;
#pragma unroll
        for (int h = 0; h < HID; h++) m += h2v[c * 16 + h] * trr[h];
        out[n * 16 + c] = x[n * 16 + c] + BETA * selu_f(acc[n * 16 + c] + bias[c] + m);
    }
}

// ---------------------------------------------------------------- launch
extern "C" void kernel_launch(void* const* d_in, const int* in_sizes, int n_in,
                              void* d_out, int out_size, void* d_ws, size_t ws_size,
                              hipStream_t stream)
{
    const float* x   = (const float*)d_in[0];
    const int*   ei  = (const int*)d_in[1];
    const float* pos = (const float*)d_in[2];

    const float* W[27];
    for (int i = 0; i < 27; i++) W[i] = (const float*)d_in[3 + i];
    // per conv c (0-based): w0=W[9c+0] b0=+1 w1=+2 b1=+3 w2=+4 b2=+5 wl=+6 bl=+7 bias=+8

    float* ws    = (float*)d_ws;
    float4* feat = (float4*)ws;                         // N_EDGES*4
    float* xcat  = ws + (size_t)N_EDGES * 4;            // N*32
    float* acc1  = xcat + (size_t)N_NODES * 32;         // N*8
    float* acc2  = acc1 + (size_t)N_NODES * 8;          // N*8
    float* acc3  = acc2 + (size_t)N_NODES * 8;          // N*16
    float* P1    = acc3 + (size_t)N_NODES * 16;
    float* P2    = P1 + P_SIZE;
    float* P3    = P2 + P_SIZE;
    float* tb    = P3 + P_SIZE;                         // N*16 (per-node t)
    float* blxb  = tb + (size_t)N_NODES * 16;           // N
    float* out   = (float*)d_out;

    hipMemsetAsync(acc1, 0, (size_t)N_NODES * 32 * sizeof(float), stream);

    PrepArgs pa;
    for (int c = 0; c < 3; c++) {
        pa.w0[c] = W[9 * c + 0]; pa.b0[c] = W[9 * c + 1];
        pa.w1[c] = W[9 * c + 2]; pa.b1[c] = W[9 * c + 3];
        pa.w2[c] = W[9 * c + 4]; pa.b2[c] = W[9 * c + 5];
    }
    pa.P[0] = P1; pa.P[1] = P2; pa.P[2] = P3;

    dim3 blk(256);
    prep_kernel<<<3, blk, 0, stream>>>(pa);
    fused_pre_kernel<<<2579, blk, 0, stream>>>(ei, pos, x, feat, xcat, W[6], W[7], tb, blxb);

    conv_kernel<8><<<5000, blk, 0, stream>>>(ei, feat, tb, blxb, P1, acc1);
    finish_mid_kernel<8, 16><<<79, blk, 0, stream>>>(acc1, W[8], P1 + OFF_H2V, tb, blxb, xcat, W[15], W[16]);

    conv_kernel<8><<<5000, blk, 0, stream>>>(ei, feat, tb, blxb, P2, acc2);
    finish_mid_kernel<8, 24><<<79, blk, 0, stream>>>(acc2, W[17], P2 + OFF_H2V, tb, blxb, xcat, W[24], W[25]);

    conv_kernel<16><<<5000, blk, 0, stream>>>(ei, feat, tb, blxb, P3, acc3);
    finish_out_kernel<<<79, blk, 0, stream>>>(acc3, W[26], P3 + OFF_H2V, tb, blxb, x, out);
}

// Round 18
// 166.546 us; speedup vs baseline: 1.0375x; 1.0375x over previous
//
#include <hip/hip_runtime.h>
#include <math.h>

#define N_NODES 20000
#define N_EDGES 320000
#define HID 16
#define OMEGA 100.0f
#define BETA 0.2f
#define REVC 0.15915494309189535f

// P layout (float/u32 indices)
#define OFF_B1  64     // 16 floats (prescaled)
#define OFF_B2  80     // 16 floats
#define OFF_A2  128    // uint4[64]: W2 A-frags, [hi|lo] K-packed
#define OFF_AO  896    // per o: 512 u32 (Ah uint4[64], Al uint4[64])
#define OFF_H2V 9088   // O*16 floats
#define P_SIZE  9472

typedef float  f32x4 __attribute__((ext_vector_type(4)));
typedef short  s16x8 __attribute__((ext_vector_type(8)));

__device__ __forceinline__ float sinrev(float x) { return __builtin_amdgcn_sinf(x); }
__device__ __forceinline__ float cosrev(float x) { return __builtin_amdgcn_cosf(x); }
__device__ __forceinline__ float fract_f(float x) { return __builtin_amdgcn_fractf(x); }

__device__ __forceinline__ float selu_f(float v) {
    const float a  = 1.6732632423543772f;
    const float sc = 1.0507009873554805f;
    return sc * (v > 0.f ? v : a * expm1f(v));
}

__device__ __forceinline__ f32x4 mfma16(s16x8 a, s16x8 b, f32x4 c) {
    return __builtin_amdgcn_mfma_f32_16x16x32_bf16(a, b, c, 0, 0, 0);
}

__device__ __forceinline__ unsigned pk_hi(float a, float b) {
    return (__float_as_uint(b) & 0xFFFF0000u) | (__float_as_uint(a) >> 16);
}
__device__ __forceinline__ float lo_of(float a) {
    return a - __uint_as_float(__float_as_uint(a) & 0xFFFF0000u);
}

union U4 { uint4 v; s16x8 s; };

// ---------------------------------------------------------------- prep (3 blocks, 1 per conv)
struct PrepArgs {
    const float* w0[3]; const float* b0[3]; const float* w1[3]; const float* b1[3];
    const float* w2[3]; const float* b2[3];
    float* P[3];
};

__global__ __launch_bounds__(256) void prep_kernel(PrepArgs A)
{
    const int OUTS[3] = {8, 8, 16};
    int c = blockIdx.x;
    int OUT = OUTS[c];
    const float* w0 = A.w0[c]; const float* b0 = A.b0[c];
    const float* w1 = A.w1[c]; const float* b1 = A.b1[c];
    const float* w2 = A.w2[c]; const float* b2 = A.b2[c];
    float* P = A.P[c];
    unsigned* Pu = (unsigned*)P;

    __shared__ float W1s[256], W2s[256], cosB[256], sinB[256], w0c[16];
    int t = threadIdx.x;
    const float s = OMEGA * REVC;
    W1s[t] = s * w1[t];
    W2s[t] = s * w2[t];
    if (t < 16) w0c[t] = s * w0[t * 4 + 3];
    __syncthreads();

    if (t < 64) { int h = t >> 2, k = t & 3; P[t] = (k < 3) ? s * w0[h * 4 + k] : s * b0[h]; }
    if (t >= 64 && t < 80)  P[t] = s * b1[t - 64];
    if (t >= 80 && t < 96)  P[t] = s * b2[t - 80];

    if (t < OUT * 16) {
        int o = t >> 4, h = t & 15;
        float ang = fract_f((float)o * w0c[h]);
        cosB[t] = cosrev(ang);
        sinB[t] = sinrev(ang);
    }
    __syncthreads();

    // W2 A-frags (K-packed hi|lo): lane (g,q), k=8q+e: e<4 -> hi(W2[g,4q+e]), e>=4 -> lo
    if (t < 64) {
        int g = t & 15, q = t >> 4;
        float w[4], l[4];
#pragma unroll
        for (int j = 0; j < 4; j++) { w[j] = W2s[g * 16 + 4 * q + j]; l[j] = lo_of(w[j]); }
        ((uint4*)(Pu + OFF_A2))[t] = make_uint4(pk_hi(w[0], w[1]), pk_hi(w[2], w[3]),
                                                pk_hi(l[0], l[1]), pk_hi(l[2], l[3]));
    }
    // Per-channel L2 A-matrices: A_o[g,k] = k<16 ? W1[g,k]*cosB[o,k] : W1[g,k-16]*sinB[o,k-16]
    for (int idx = t; idx < OUT * 64; idx += 256) {
        int o = idx >> 6, lane = idx & 63, g = lane & 15, q = lane >> 4;
        float v[8], l[8];
#pragma unroll
        for (int e = 0; e < 8; e++) {
            int k = 8 * q + e;
            float a = (k < 16) ? W1s[g * 16 + k] * cosB[o * 16 + k]
                               : W1s[g * 16 + (k - 16)] * sinB[o * 16 + (k - 16)];
            v[e] = a; l[e] = lo_of(a);
        }
        ((uint4*)(Pu + OFF_AO + o * 512))[lane] =
            make_uint4(pk_hi(v[0], v[1]), pk_hi(v[2], v[3]), pk_hi(v[4], v[5]), pk_hi(v[6], v[7]));
        ((uint4*)(Pu + OFF_AO + o * 512 + 256))[lane] =
            make_uint4(pk_hi(l[0], l[1]), pk_hi(l[2], l[3]), pk_hi(l[4], l[5]), pk_hi(l[6], l[7]));
    }
    // self-loop h2 chain (feat=0), fp32 exact
    if (t < OUT) {
        float oc = (float)t;
        float h0[HID], h1[HID];
#pragma unroll
        for (int h = 0; h < HID; h++)
            h0[h] = sinrev(fract_f(fmaf(oc, w0c[h], s * b0[h])));
#pragma unroll
        for (int g = 0; g < HID; g++) {
            float sa = s * b1[g];
#pragma unroll
            for (int h = 0; h < HID; h++) sa += h0[h] * W1s[g * HID + h];
            h1[g] = sinrev(sa);
        }
#pragma unroll
        for (int g = 0; g < HID; g++) {
            float sa = s * b2[g];
#pragma unroll
            for (int h = 0; h < HID; h++) sa += h1[h] * W2s[g * HID + h];
            P[OFF_H2V + t * HID + g] = sinrev(sa);
        }
    }
}

// ---------------------------------------------------------------- fused pre: feat + xcat + tself1
__global__ __launch_bounds__(256) void fused_pre_kernel(
    const int* __restrict__ ei, const float* __restrict__ pos,
    const float* __restrict__ x,
    float4* __restrict__ feat, float* __restrict__ xcat,
    const float* __restrict__ wl1, const float* __restrict__ bl1,
    float* __restrict__ tb, float* __restrict__ blxb)
{
    int b = blockIdx.x;
    if (b < 1250) {
        int e = b * 256 + threadIdx.x;
        if (e >= N_EDGES) return;
        int s = ei[e], d = ei[N_EDGES + e];
        float rx = pos[d * 3 + 0] - pos[s * 3 + 0];
        float ry = pos[d * 3 + 1] - pos[s * 3 + 1];
        float rz = pos[d * 3 + 2] - pos[s * 3 + 2];
        float sq = rx * rx + ry * ry + rz * rz;
        float4 f = make_float4(0.f, 0.f, 0.f, 0.f);
        if (sq > 0.f) {
            float rho = sqrtf(sq);
            float th  = atan2f(ry, rx);
            float ph  = asinf(fminf(fmaxf(rz / rho, -1.f), 1.f));
            const float inv_pi = 0.31830988618379067f;
            f = make_float4(rho, th * inv_pi, ph * inv_pi, 0.f);
        }
        feat[e] = f;
    } else if (b < 2500) {
        int i = (b - 1250) * 256 + threadIdx.x;
        if (i >= N_NODES * 16) return;
        int n = i >> 4, cc = i & 15;
        xcat[n * 32 + cc] = x[i];
    } else {
        int n = (b - 2500) * 256 + threadIdx.x;
        if (n >= N_NODES) return;
        float tn[HID];
#pragma unroll
        for (int h = 0; h < HID; h++) tn[h] = 0.f;
        float bx = 0.f;
#pragma unroll
        for (int i = 0; i < 16; i++) {
            float xi = x[n * 16 + i];
            bx += bl1[i] * xi;
#pragma unroll
            for (int h = 0; h < HID; h++) tn[h] += wl1[i * 16 + h] * xi;
        }
#pragma unroll
        for (int h = 0; h < HID; h++) tb[n * 16 + h] = tn[h];
        blxb[n] = bx;
    }
}

// ---------------------------------------------------------------- conv: wave = 16 edges, loop o
// T and bx gathered from per-node tables; per-o per-q partials to LDS (layout
// (q*OUT+o)*17+e16); epilogue sums q-partials during transposed channel-contiguous
// atomic emission.
template<int OUT>
__global__ __launch_bounds__(256) void conv_kernel(
    const int* __restrict__ ei, const float4* __restrict__ feat,
    const float* __restrict__ tbn, const float* __restrict__ blxn,
    const float* __restrict__ P, float* __restrict__ acc)
{
    constexpr int L2O = (OUT == 16) ? 4 : 3;
    constexpr int EPI = 64 / OUT;     // edges per atomic instruction
    constexpr int NI  = 16 / EPI;     // atomic instructions per wave

    __shared__ float sm[4][OUT * 4 * 17];
    const unsigned* Pu = (const unsigned*)P;
    int wslot = threadIdx.x >> 6;
    int wid  = (blockIdx.x * 256 + threadIdx.x) >> 6;
    int lane = threadIdx.x & 63;
    int e16 = lane & 15, q = lane >> 4;
    int e = wid * 16 + e16;
    int src = ei[e];
    int dst = ei[N_EDGES + e];
    float4 f = feat[e];

    // T, bx: gathered from per-node tables (exact fp32)
    f32x4 T = *(const f32x4*)(tbn + src * 16 + 4 * q);
    float bx = blxn[src];

    // L1: 8 angles (h-octet (q&1)*8); q<2 -> sin, q>=2 -> cos. B-frag k=8q+e.
    float tr[8];
    {
        const float4* w0i = (const float4*)P;
        int hb = (q & 1) * 8;
#pragma unroll
        for (int j = 0; j < 8; j++) {
            float4 w = w0i[hb + j];
            float ang = fract_f(w.w + f.x * w.x + f.y * w.y + f.z * w.z);
            tr[j] = (q < 2) ? sinrev(ang) : cosrev(ang);
        }
    }
    U4 Bh, Bl;
    Bh.v = make_uint4(pk_hi(tr[0], tr[1]), pk_hi(tr[2], tr[3]),
                      pk_hi(tr[4], tr[5]), pk_hi(tr[6], tr[7]));
    Bl.v = make_uint4(pk_hi(lo_of(tr[0]), lo_of(tr[1])), pk_hi(lo_of(tr[2]), lo_of(tr[3])),
                      pk_hi(lo_of(tr[4]), lo_of(tr[5])), pk_hi(lo_of(tr[6]), lo_of(tr[7])));

    U4 A2; A2.v = ((const uint4*)(Pu + OFF_A2))[lane];
    f32x4 c1 = *(const f32x4*)(P + OFF_B1 + 4 * q);
    f32x4 c2 = *(const f32x4*)(P + OFF_B2 + 4 * q);

#pragma unroll 2
    for (int o = 0; o < OUT; ++o) {
        U4 Ah, Al;
        Ah.v = ((const uint4*)(Pu + OFF_AO + o * 512))[lane];
        Al.v = ((const uint4*)(Pu + OFF_AO + o * 512 + 256))[lane];
        f32x4 D = c1;
        D = mfma16(Ah.s, Bh.s, D);
        D = mfma16(Ah.s, Bl.s, D);
        D = mfma16(Al.s, Bh.s, D);
        float h1[4];
#pragma unroll
        for (int j = 0; j < 4; j++) h1[j] = sinrev(D[j]);
        unsigned p0 = pk_hi(h1[0], h1[1]), p1 = pk_hi(h1[2], h1[3]);
        unsigned l0 = pk_hi(lo_of(h1[0]), lo_of(h1[1])), l1 = pk_hi(lo_of(h1[2]), lo_of(h1[3]));
        U4 Ph, Pl;
        Ph.v = make_uint4(p0, p1, p0, p1);
        Pl.v = make_uint4(l0, l1, l0, l1);
        f32x4 D2 = c2;
        D2 = mfma16(A2.s, Ph.s, D2);
        D2 = mfma16(A2.s, Pl.s, D2);
        // per-q partial straight to LDS (no cross-lane reduce here)
        float p = sinrev(D2[0]) * T[0] + sinrev(D2[1]) * T[1]
                + sinrev(D2[2]) * T[2] + sinrev(D2[3]) * T[3];
        if (q == 0) p += bx;
        sm[wslot][(q * OUT + o) * 17 + e16] = p;
    }

    // transposed atomic emission: lane = (edge-in-group, channel); sum 4 q-partials
    int oo = lane & (OUT - 1);
    int el = lane >> L2O;
#pragma unroll
    for (int j = 0; j < NI; j++) {
        int ej = j * EPI + el;
        int dj = __shfl(dst, ej);
        float v = sm[wslot][(0 * OUT + oo) * 17 + ej] + sm[wslot][(1 * OUT + oo) * 17 + ej]
                + sm[wslot][(2 * OUT + oo) * 17 + ej] + sm[wslot][(3 * OUT + oo) * 17 + ej];
        atomicAdd(&acc[dj * OUT + oo], v);
    }
}

// ---------------------------------------------------------------- finishers (per node)
template<int OUT, int CO>
__global__ __launch_bounds__(256) void finish_mid_kernel(
    const float* __restrict__ acc, const float* __restrict__ bias,
    const float* __restrict__ h2v,
    float* __restrict__ tb, float* __restrict__ blxb,
    float* __restrict__ xcat,
    const float* __restrict__ wlN, const float* __restrict__ blN)
{
    int n = blockIdx.x * 256 + threadIdx.x;
    if (n >= N_NODES) return;
    float trr[HID];
#pragma unroll
    for (int h = 0; h < HID; h++) trr[h] = tb[n * 16 + h];
    float bx = blxb[n];
    float xrow[CO + OUT];
#pragma unroll
    for (int i = 0; i < CO; i++) xrow[i] = xcat[n * 32 + i];
#pragma unroll
    for (int o = 0; o < OUT; o++) {
        float m = bx;
#pragma unroll
        for (int h = 0; h < HID; h++) m += h2v[o * 16 + h] * trr[h];
        float v = selu_f(acc[n * OUT + o] + bias[o] + m);
        xrow[CO + o] = v;
        xcat[n * 32 + CO + o] = v;
    }
    float tn[HID];
#pragma unroll
    for (int h = 0; h < HID; h++) tn[h] = 0.f;
    float bxn = 0.f;
#pragma unroll
    for (int i = 0; i < CO + OUT; i++) {
        float xi = xrow[i];
        bxn += blN[i] * xi;
#pragma unroll
        for (int h = 0; h < HID; h++) tn[h] += wlN[i * 16 + h] * xi;
    }
#pragma unroll
    for (int h = 0; h < HID; h++) tb[n * 16 + h] = tn[h];
    blxb[n] = bxn;
}

__global__ __launch_bounds__(256) void finish_out_kernel(
    const float* __restrict__ acc, const float* __restrict__ bias,
    const float* __restrict__ h2v,
    const float* __restrict__ tb, const float* __restrict__ blxb,
    const float* __restrict__ x, float* __restrict__ out)
{
    int n = blockIdx.x * 256 + threadIdx.x;
    if (n >= N_NODES) return;
    float trr[HID];
#pragma unroll
    for (int h = 0; h < HID; h++) trr[h] = tb[n * 16 + h];
    float bx = blxb[n];
#pragma unroll
    for (int c = 0; c < 16; c++) {
        float m = bx;
#pragma unroll
        for (int h = 0; h < HID; h++) m += h2v[c * 16 + h] * trr[h];
        out[n * 16 + c] = x[n * 16 + c] + BETA * selu_f(acc[n * 16 + c] + bias[c] + m);
    }
}

// ---------------------------------------------------------------- launch
extern "C" void kernel_launch(void* const* d_in, const int* in_sizes, int n_in,
                              void* d_out, int out_size, void* d_ws, size_t ws_size,
                              hipStream_t stream)
{
    const float* x   = (const float*)d_in[0];
    const int*   ei  = (const int*)d_in[1];
    const float* pos = (const float*)d_in[2];

    const float* W[27];
    for (int i = 0; i < 27; i++) W[i] = (const float*)d_in[3 + i];
    // per conv c (0-based): w0=W[9c+0] b0=+1 w1=+2 b1=+3 w2=+4 b2=+5 wl=+6 bl=+7 bias=+8

    float* ws    = (float*)d_ws;
    float4* feat = (float4*)ws;                         // N_EDGES*4
    float* xcat  = ws + (size_t)N_EDGES * 4;            // N*32
    float* acc1  = xcat + (size_t)N_NODES * 32;         // N*8
    float* acc2  = acc1 + (size_t)N_NODES * 8;          // N*8
    float* acc3  = acc2 + (size_t)N_NODES * 8;          // N*16
    float* P1    = acc3 + (size_t)N_NODES * 16;
    float* P2    = P1 + P_SIZE;
    float* P3    = P2 + P_SIZE;
    float* tb    = P3 + P_SIZE;                         // N*16 (per-node t)
    float* blxb  = tb + (size_t)N_NODES * 16;           // N
    float* out   = (float*)d_out;

    hipMemsetAsync(acc1, 0, (size_t)N_NODES * 32 * sizeof(float), stream);

    PrepArgs pa;
    for (int c = 0; c < 3; c++) {
        pa.w0[c] = W[9 * c + 0]; pa.b0[c] = W[9 * c + 1];
        pa.w1[c] = W[9 * c + 2]; pa.b1[c] = W[9 * c + 3];
        pa.w2[c] = W[9 * c + 4]; pa.b2[c] = W[9 * c + 5];
    }
    pa.P[0] = P1; pa.P[1] = P2; pa.P[2] = P3;

    dim3 blk(256);
    prep_kernel<<<3, blk, 0, stream>>>(pa);
    fused_pre_kernel<<<2579, blk, 0, stream>>>(ei, pos, x, feat, xcat, W[6], W[7], tb, blxb);

    conv_kernel<8><<<5000, blk, 0, stream>>>(ei, feat, tb, blxb, P1, acc1);
    finish_mid_kernel<8, 16><<<79, blk, 0, stream>>>(acc1, W[8], P1 + OFF_H2V, tb, blxb, xcat, W[15], W[16]);

    conv_kernel<8><<<5000, blk, 0, stream>>>(ei, feat, tb, blxb, P2, acc2);
    finish_mid_kernel<8, 24><<<79, blk, 0, stream>>>(acc2, W[17], P2 + OFF_H2V, tb, blxb, xcat, W[24], W[25]);

    conv_kernel<16><<<5000, blk, 0, stream>>>(ei, feat, tb, blxb, P3, acc3);
    finish_out_kernel<<<79, blk, 0, stream>>>(acc3, W[26], P3 + OFF_H2V, tb, blxb, x, out);
}